// Round 5
// baseline (1339.146 us; speedup 1.0000x reference)
//
#include <hip/hip_runtime.h>
#include <hip/hip_cooperative_groups.h>

namespace cg = cooperative_groups;

// OctreeDWConvBn: out[n,c] = BN_c( sum_k data[neigh[n,k],c] * weight[k,c] )
// N=131072, C=192, K=27. fp32 in/out; gathered operand staged as bf16.
// R9: single cooperative persistent kernel (2048 blocks x 192 thr, 8/CU).
//   A: fp32->bf16 stage (grid-stride)            [removes kernel gap]
//   B: conv, 2 node-groups/block; per-block BN partials stored to `out`
//      (scratch) -> NO global atomic drain        [removes RMW serialization]
//   C: 16-block partial reduce -> stats (6144 cheap atomics)
//   D: BN finalize+apply (uint4 in / 2x float4 out)
// grid.sync() + __threadfence() between phases (device-scope visibility,
// cross-XCD safe). Fallback: proven R8 3-kernel path if coop launch refused.
// Evidence base: conv pinned at 3.26 TB/s / 624 MB regardless of occupancy
// (R4=42%, R8=58%) -> don't touch gather shape; attack the ~198 us that two
// 150-MB streaming kernels + gaps were costing.

static constexpr int NN   = 131072;   // nodes
static constexpr int CC   = 192;      // channels
static constexpr int KK   = 27;       // stencil taps
static constexpr int NB   = 32;       // nodes per conv group (serial)
static constexpr int GRID = 2048;     // co-resident blocks (8/CU x 256 CU)
static constexpr int TPB  = 192;      // 3 waves
static constexpr float BN_EPS = 1e-5f;

typedef float          f32x4 __attribute__((ext_vector_type(4)));
typedef unsigned short u16x4 __attribute__((ext_vector_type(4)));
typedef unsigned int   u32x4 __attribute__((ext_vector_type(4)));

__device__ __forceinline__ unsigned short f2bf_rne(float x) {
    unsigned u = __float_as_uint(x);
    return (unsigned short)((u + 0x7FFFu + ((u >> 16) & 1u)) >> 16);
}
__device__ __forceinline__ float bf2f(unsigned short b) {
    return __uint_as_float((unsigned)b << 16);
}

// ---------------------------------------------------------------------------
// R9 fused cooperative kernel.
// ---------------------------------------------------------------------------
__global__ __launch_bounds__(TPB, 6) void fused_all(
    const float* __restrict__ data,      // [NN, CC] fp32
    const int*   __restrict__ neigh,     // [NN, KK]
    const float* __restrict__ weight,    // [KK, CC]
    const float* __restrict__ gamma,
    const float* __restrict__ beta,
    float*       __restrict__ out,       // [NN, CC] fp32 (phase B/C scratch!)
    unsigned short* __restrict__ data_bf, // ws [NN, CC] bf16 bits
    unsigned short* __restrict__ conv_bf, // ws [NN, CC] bf16 bits
    float*       __restrict__ stats)     // ws [384] = sum | sumsq
{
    cg::grid_group grid = cg::this_grid();
    const int t   = threadIdx.x;
    const int bid = blockIdx.x;
    float* partials = out;               // scratch [GRID][384], dead before D

    // ---- Phase A: fp32 -> bf16 staging + zero stats --------------------
    if (bid < 2) stats[bid * TPB + t] = 0.f;
    {
        const int tot    = NN * CC / 4;          // float4 count
        const int stride = GRID * TPB;
        for (int i = bid * TPB + t; i < tot; i += stride) {
            const f32x4 v = reinterpret_cast<const f32x4*>(data)[i];
            u16x4 o;
            o.x = f2bf_rne(v.x); o.y = f2bf_rne(v.y);
            o.z = f2bf_rne(v.z); o.w = f2bf_rne(v.w);
            reinterpret_cast<u16x4*>(data_bf)[i] = o;
        }
    }
    __threadfence();
    grid.sync();

    // ---- Phase B: depthwise conv + per-block partial sums --------------
    {
        float w[KK];
#pragma unroll
        for (int k = 0; k < KK; ++k) w[k] = weight[k * CC + t];

        float s = 0.f, ss = 0.f;
#pragma unroll 1
        for (int gidx = 0; gidx < 2; ++gidx) {
            const int base = (bid + gidx * GRID) * NB;
            for (int n = 0; n < NB; ++n) {
                const int node = base + n;                   // block-uniform
                const int* nrow = neigh + (size_t)node * KK; // -> s_load

                unsigned short r[KK];
#pragma unroll
                for (int k = 0; k < KK; ++k)
                    r[k] = data_bf[(size_t)nrow[k] * CC + t];

                float acc = 0.f;
#pragma unroll
                for (int k = 0; k < KK; ++k)
                    acc = fmaf(bf2f(r[k]), w[k], acc);

                conv_bf[(size_t)node * CC + t] = f2bf_rne(acc);
                s  += acc;
                ss += acc * acc;
            }
        }
        partials[bid * 384 + t]       = s;    // coalesced 1536 B / block
        partials[bid * 384 + 192 + t] = ss;
    }
    __threadfence();
    grid.sync();

    // ---- Phase C: reduce [GRID][384] partials -> stats[384] ------------
    if (bid < 16) {
        float a0 = 0.f, a1 = 0.f;
        const int r0 = bid * (GRID / 16);
        for (int r = r0; r < r0 + GRID / 16; ++r) {
            a0 += partials[r * 384 + t];
            a1 += partials[r * 384 + 192 + t];
        }
        atomicAdd(&stats[t],       a0);   // 16 collisions/address: trivial
        atomicAdd(&stats[192 + t], a1);
    }
    __threadfence();
    grid.sync();

    // ---- Phase D: BN finalize + apply ----------------------------------
    {
        const int cb = (t % 24) * 8;      // this thread's channel octet
        const float inv_n = 1.0f / (float)NN;
        float sc[8], bi[8];
#pragma unroll
        for (int j = 0; j < 8; ++j) {
            const float m = stats[cb + j] * inv_n;
            const float v = stats[192 + cb + j] * inv_n - m * m;
            sc[j] = gamma[cb + j] * rsqrtf(v + BN_EPS);
            bi[j] = beta[cb + j] - m * sc[j];
        }

        const u32x4* __restrict__ conv_u4 =
            reinterpret_cast<const u32x4*>(conv_bf);
        f32x4* __restrict__ out4 = reinterpret_cast<f32x4*>(out);
        for (int nb = bid; nb < NN / 8; nb += GRID) {
            const int i8 = nb * TPB + t;            // linear in t: coalesced
            const u32x4 u = conv_u4[i8];
            f32x4 a, b;
            a.x = fmaf(__uint_as_float(u.x << 16),         sc[0], bi[0]);
            a.y = fmaf(__uint_as_float(u.x & 0xFFFF0000u), sc[1], bi[1]);
            a.z = fmaf(__uint_as_float(u.y << 16),         sc[2], bi[2]);
            a.w = fmaf(__uint_as_float(u.y & 0xFFFF0000u), sc[3], bi[3]);
            b.x = fmaf(__uint_as_float(u.z << 16),         sc[4], bi[4]);
            b.y = fmaf(__uint_as_float(u.z & 0xFFFF0000u), sc[5], bi[5]);
            b.z = fmaf(__uint_as_float(u.w << 16),         sc[6], bi[6]);
            b.w = fmaf(__uint_as_float(u.w & 0xFFFF0000u), sc[7], bi[7]);
            out4[2 * i8]     = a;
            out4[2 * i8 + 1] = b;
        }
    }
}

// ---------------------------------------------------------------------------
// Fallback path A (coop refused): proven R8 3-kernel pipeline.
// ---------------------------------------------------------------------------
__global__ __launch_bounds__(256) void cvt_zero(
    const float* __restrict__ src, unsigned short* __restrict__ dst,
    float* __restrict__ stats)
{
    if (blockIdx.x < 2 && threadIdx.x < CC)
        stats[blockIdx.x * CC + threadIdx.x] = 0.f;
    const int tot    = NN * CC / 4;
    const int stride = gridDim.x * 256;
    for (int i = blockIdx.x * 256 + threadIdx.x; i < tot; i += stride) {
        const f32x4 v = reinterpret_cast<const f32x4*>(src)[i];
        u16x4 o;
        o.x = f2bf_rne(v.x); o.y = f2bf_rne(v.y);
        o.z = f2bf_rne(v.z); o.w = f2bf_rne(v.w);
        reinterpret_cast<u16x4*>(dst)[i] = o;
    }
}

__global__ __launch_bounds__(192, 6) void conv_r8(
    const unsigned short* __restrict__ data_bf,
    const int*   __restrict__ neigh,
    const float* __restrict__ weight,
    unsigned short* __restrict__ conv_bf,
    float*       __restrict__ ch_sum,
    float*       __restrict__ ch_sumsq)
{
    const int c    = threadIdx.x;
    const int base = blockIdx.x * NB;
    float w[KK];
#pragma unroll
    for (int k = 0; k < KK; ++k) w[k] = weight[k * CC + c];
    float s = 0.f, ss = 0.f;
    for (int n = 0; n < NB; ++n) {
        const int node = base + n;
        const int* nrow = neigh + (size_t)node * KK;
        unsigned short r[KK];
#pragma unroll
        for (int k = 0; k < KK; ++k)
            r[k] = data_bf[(size_t)nrow[k] * CC + c];
        float acc = 0.f;
#pragma unroll
        for (int k = 0; k < KK; ++k)
            acc = fmaf(bf2f(r[k]), w[k], acc);
        conv_bf[(size_t)node * CC + c] = f2bf_rne(acc);
        s  += acc;
        ss += acc * acc;
    }
    atomicAdd(&ch_sum[c],   s);
    atomicAdd(&ch_sumsq[c], ss);
}

__global__ __launch_bounds__(192) void bn_apply_fused(
    const u32x4* __restrict__ conv_u4,
    const float* __restrict__ ch_sum,
    const float* __restrict__ ch_sumsq,
    const float* __restrict__ gamma,
    const float* __restrict__ beta,
    float* __restrict__ out)
{
    const int t  = threadIdx.x;
    const int cb = (t % 24) * 8;
    const float inv_n = 1.0f / (float)NN;
    float sc[8], bi[8];
#pragma unroll
    for (int j = 0; j < 8; ++j) {
        const float m = ch_sum[cb + j] * inv_n;
        const float v = ch_sumsq[cb + j] * inv_n - m * m;
        sc[j] = gamma[cb + j] * rsqrtf(v + BN_EPS);
        bi[j] = beta[cb + j] - m * sc[j];
    }
    f32x4* __restrict__ out4 = reinterpret_cast<f32x4*>(out);
    for (int nb = blockIdx.x; nb < NN / 8; nb += gridDim.x) {
        const int i8 = nb * 192 + t;
        const u32x4 u = conv_u4[i8];
        f32x4 a, b;
        a.x = fmaf(__uint_as_float(u.x << 16),         sc[0], bi[0]);
        a.y = fmaf(__uint_as_float(u.x & 0xFFFF0000u), sc[1], bi[1]);
        a.z = fmaf(__uint_as_float(u.y << 16),         sc[2], bi[2]);
        a.w = fmaf(__uint_as_float(u.y & 0xFFFF0000u), sc[3], bi[3]);
        b.x = fmaf(__uint_as_float(u.z << 16),         sc[4], bi[4]);
        b.y = fmaf(__uint_as_float(u.z & 0xFFFF0000u), sc[5], bi[5]);
        b.z = fmaf(__uint_as_float(u.w << 16),         sc[6], bi[6]);
        b.w = fmaf(__uint_as_float(u.w & 0xFFFF0000u), sc[7], bi[7]);
        out4[2 * i8]     = a;
        out4[2 * i8 + 1] = b;
    }
}

// ---------------------------------------------------------------------------
// Fallback path B (ws too small): fp32 conv + fused apply on fp32.
// ---------------------------------------------------------------------------
__global__ __launch_bounds__(CC) void conv_bn_partial_f32(
    const float* __restrict__ data,
    const int*   __restrict__ neigh,
    const float* __restrict__ weight,
    float*       __restrict__ conv_out,
    float*       __restrict__ ch_sum,
    float*       __restrict__ ch_sumsq)
{
    const int c = threadIdx.x;
    const int base = blockIdx.x * NB;
    float w[KK];
#pragma unroll
    for (int k = 0; k < KK; ++k) w[k] = weight[k * CC + c];
    float s = 0.f, ss = 0.f;
    for (int n = 0; n < NB; ++n) {
        const int node = base + n;
        const int* nrow = neigh + node * KK;
        float acc = 0.f;
#pragma unroll
        for (int k = 0; k < KK; ++k)
            acc = fmaf(data[nrow[k] * CC + c], w[k], acc);
        conv_out[node * CC + c] = acc;
        s += acc; ss += acc * acc;
    }
    atomicAdd(&ch_sum[c], s);
    atomicAdd(&ch_sumsq[c], ss);
}

__global__ __launch_bounds__(192) void bn_apply_f32_fused(
    float* __restrict__ out,
    const float* __restrict__ ch_sum,
    const float* __restrict__ ch_sumsq,
    const float* __restrict__ gamma,
    const float* __restrict__ beta)
{
    const int t = threadIdx.x;
    const int g = t / 48;
    const int q = t - g * 48;
    const int cb = q * 4;
    const float inv_n = 1.0f / (float)NN;
    float4 sc, bi;
    float m0 = ch_sum[cb+0]*inv_n, m1 = ch_sum[cb+1]*inv_n;
    float m2 = ch_sum[cb+2]*inv_n, m3 = ch_sum[cb+3]*inv_n;
    sc.x = gamma[cb+0]*rsqrtf(ch_sumsq[cb+0]*inv_n - m0*m0 + BN_EPS);
    sc.y = gamma[cb+1]*rsqrtf(ch_sumsq[cb+1]*inv_n - m1*m1 + BN_EPS);
    sc.z = gamma[cb+2]*rsqrtf(ch_sumsq[cb+2]*inv_n - m2*m2 + BN_EPS);
    sc.w = gamma[cb+3]*rsqrtf(ch_sumsq[cb+3]*inv_n - m3*m3 + BN_EPS);
    bi.x = beta[cb+0] - m0*sc.x; bi.y = beta[cb+1] - m1*sc.y;
    bi.z = beta[cb+2] - m2*sc.z; bi.w = beta[cb+3] - m3*sc.w;
    for (int nb = blockIdx.x; nb < NN / 4; nb += gridDim.x) {
        const int i = (nb * 4 + g) * 48 + q;
        float4 v = reinterpret_cast<float4*>(out)[i];
        v.x = fmaf(v.x, sc.x, bi.x); v.y = fmaf(v.y, sc.y, bi.y);
        v.z = fmaf(v.z, sc.z, bi.z); v.w = fmaf(v.w, sc.w, bi.w);
        reinterpret_cast<float4*>(out)[i] = v;
    }
}

extern "C" void kernel_launch(void* const* d_in, const int* in_sizes, int n_in,
                              void* d_out, int out_size, void* d_ws, size_t ws_size,
                              hipStream_t stream) {
    const float* data   = (const float*)d_in[0];
    const int*   neigh  = (const int*)  d_in[1];
    const float* weight = (const float*)d_in[2];
    const float* gamma  = (const float*)d_in[3];
    const float* beta   = (const float*)d_in[4];
    float* out = (float*)d_out;

    // ws: stats 384 floats (padded to 4096 B) | data_bf 50.3 MB | conv_bf 50.3 MB
    float* stats    = (float*)d_ws;
    float* ch_sum   = stats;
    float* ch_sumsq = stats + CC;
    unsigned short* data_bf = (unsigned short*)((char*)d_ws + 4096);
    const size_t stage_bytes = (size_t)NN * CC * sizeof(unsigned short);
    unsigned short* conv_bf =
        (unsigned short*)((char*)d_ws + 4096 + stage_bytes);

    const size_t need_full = 4096 + 2 * stage_bytes;

    if (ws_size >= need_full) {
        void* args[] = {
            (void*)&data, (void*)&neigh, (void*)&weight, (void*)&gamma,
            (void*)&beta, (void*)&out, (void*)&data_bf, (void*)&conv_bf,
            (void*)&stats };
        hipError_t err = hipLaunchCooperativeKernel(
            (const void*)fused_all, dim3(GRID), dim3(TPB), args, 0, stream);
        if (err != hipSuccess) {
            // Coop refused: proven R8 3-kernel path.
            cvt_zero<<<4096, 256, 0, stream>>>(data, data_bf, stats);
            conv_r8<<<NN / NB, 192, 0, stream>>>(
                data_bf, neigh, weight, conv_bf, ch_sum, ch_sumsq);
            bn_apply_fused<<<4096, 192, 0, stream>>>(
                (const u32x4*)conv_bf, ch_sum, ch_sumsq, gamma, beta, out);
        }
    } else {
        hipMemsetAsync(stats, 0, 2 * CC * sizeof(float), stream);
        conv_bn_partial_f32<<<NN / NB, CC, 0, stream>>>(
            data, neigh, weight, out, ch_sum, ch_sumsq);
        bn_apply_f32_fused<<<8192, 192, 0, stream>>>(
            out, ch_sum, ch_sumsq, gamma, beta);
    }
}

// Round 6
// 402.050 us; speedup vs baseline: 3.3308x; 3.3308x over previous
//
#include <hip/hip_runtime.h>

// OctreeDWConvBn: out[n,c] = BN_c( sum_k data[neigh[n,k],c] * weight[k,c] )
// N=131072, C=192, K=27. fp32 in/out; gathered operand staged as bf16.
// R10: revert R9's cooperative fusion (kernel-wide rate collapse: 753 GB/s,
// VALUBusy 5%, 1227 us). Restore the proven R8 3-kernel pipeline and apply
// the last safe levers:
//   cvt : 32 B/lane NT reads + 16 B/lane writes (u16x8), grid 2048
//   conv: NB 32->64 (grid 2048 = exact full residency at 8 blk/CU),
//         halves atomic count to 786K / collisions to 2048 per address
//   bn  : unchanged (16 B in / 32 B out per lane, proven shape)
// Evidence base: conv pinned at ~3.3 TB/s / 624 MB fetch across occupancy
// 42->58% (null) and channel-split (negative); harness overhead ~112 us
// (R9: bench 1339 vs kernel 1227); cvt+bn+gaps ~= 73 us.

static constexpr int NN = 131072;   // nodes
static constexpr int CC = 192;      // channels
static constexpr int KK = 27;       // stencil taps
static constexpr int NB = 64;       // nodes per conv block (serial)
static constexpr float BN_EPS = 1e-5f;

typedef float          f32x4 __attribute__((ext_vector_type(4)));
typedef unsigned short u16x4 __attribute__((ext_vector_type(4)));
typedef unsigned short u16x8 __attribute__((ext_vector_type(8)));
typedef unsigned int   u32x4 __attribute__((ext_vector_type(4)));

__device__ __forceinline__ unsigned short f2bf_rne(float x) {
    unsigned u = __float_as_uint(x);
    return (unsigned short)((u + 0x7FFFu + ((u >> 16) & 1u)) >> 16);
}
__device__ __forceinline__ float bf2f(unsigned short b) {
    return __uint_as_float((unsigned)b << 16);
}

// ---------------------------------------------------------------------------
// Kernel 1: fp32 -> bf16 staging + zero stat buffers.
// 2048 blocks x 256 thr, 6 iterations/thread: per iter 2x f32x4 NT load
// (32 B/lane) -> one u16x8 store (16 B/lane). fp32 source dead after this.
// ---------------------------------------------------------------------------
__global__ __launch_bounds__(256) void cvt_zero(
    const float* __restrict__ src, unsigned short* __restrict__ dst,
    float* __restrict__ stats /* [2*CC] sum|sumsq */)
{
    if (blockIdx.x < 2 && threadIdx.x < CC)
        stats[blockIdx.x * CC + threadIdx.x] = 0.f;

    const int tot    = NN * CC / 8;                 // u16x8 count
    const int stride = gridDim.x * 256;
    const f32x4* __restrict__ src4 = reinterpret_cast<const f32x4*>(src);
    u16x8* __restrict__ dst8 = reinterpret_cast<u16x8*>(dst);
    for (int i = blockIdx.x * 256 + threadIdx.x; i < tot; i += stride) {
        const f32x4 a = __builtin_nontemporal_load(src4 + 2 * i);
        const f32x4 b = __builtin_nontemporal_load(src4 + 2 * i + 1);
        u16x8 o;
        o.s0 = f2bf_rne(a.x); o.s1 = f2bf_rne(a.y);
        o.s2 = f2bf_rne(a.z); o.s3 = f2bf_rne(a.w);
        o.s4 = f2bf_rne(b.x); o.s5 = f2bf_rne(b.y);
        o.s6 = f2bf_rne(b.z); o.s7 = f2bf_rne(b.w);
        dst8[i] = o;
    }
}

// ---------------------------------------------------------------------------
// Kernel 2: depthwise conv + per-block partial BN sums (R8's proven gather
// shape: 192 thr = thread-per-channel, 3 waves fetch the 3 x 128-B lines of
// each 384-B row simultaneously; weights in 27 VGPRs, zero LDS/barriers).
// NB=64 -> grid 2048 (exactly 8 blocks/CU co-resident), atomics halved.
// ---------------------------------------------------------------------------
__global__ __launch_bounds__(192, 6) void conv_r10(
    const unsigned short* __restrict__ data_bf,   // [NN, CC] bf16 bits
    const int*   __restrict__ neigh,              // [NN, KK]
    const float* __restrict__ weight,             // [KK, CC]
    unsigned short* __restrict__ conv_bf,         // [NN, CC] bf16 bits (ws)
    float*       __restrict__ ch_sum,             // [CC]
    float*       __restrict__ ch_sumsq)           // [CC]
{
    const int c    = threadIdx.x;
    const int base = blockIdx.x * NB;

    float w[KK];
#pragma unroll
    for (int k = 0; k < KK; ++k) w[k] = weight[k * CC + c];

    float s = 0.f, ss = 0.f;

    for (int n = 0; n < NB; ++n) {
        const int node = base + n;                   // block-uniform
        const int* nrow = neigh + (size_t)node * KK; // uniform -> s_load

        unsigned short r[KK];
#pragma unroll
        for (int k = 0; k < KK; ++k)
            r[k] = data_bf[(size_t)nrow[k] * CC + c];

        float acc = 0.f;
#pragma unroll
        for (int k = 0; k < KK; ++k)
            acc = fmaf(bf2f(r[k]), w[k], acc);

        __builtin_nontemporal_store(f2bf_rne(acc),
                                    &conv_bf[(size_t)node * CC + c]);
        s  += acc;
        ss += acc * acc;
    }

    atomicAdd(&ch_sum[c],   s);
    atomicAdd(&ch_sumsq[c], ss);
}

// ---------------------------------------------------------------------------
// Kernel 3: fused BN finalize + normalize (proven R8 shape).
// t = channel octet (t%24)*8; per iter one u32x4 load (8 bf16, 16 B/lane)
// + two f32x4 stores (32 B/lane); block footprint linear/coalesced.
// ---------------------------------------------------------------------------
__global__ __launch_bounds__(192) void bn_apply_fused(
    const u32x4* __restrict__ conv_u4,   // [NN*24] uint4 (8 bf16 each)
    const float* __restrict__ ch_sum,
    const float* __restrict__ ch_sumsq,
    const float* __restrict__ gamma,
    const float* __restrict__ beta,
    float* __restrict__ out)             // [NN, CC]
{
    const int t  = threadIdx.x;
    const int cb = (t % 24) * 8;

    const float inv_n = 1.0f / (float)NN;
    float sc[8], bi[8];
#pragma unroll
    for (int j = 0; j < 8; ++j) {
        const float m = ch_sum[cb + j] * inv_n;
        const float v = ch_sumsq[cb + j] * inv_n - m * m;
        sc[j] = gamma[cb + j] * rsqrtf(v + BN_EPS);
        bi[j] = beta[cb + j] - m * sc[j];
    }

    f32x4* __restrict__ out4 = reinterpret_cast<f32x4*>(out);
    for (int nb = blockIdx.x; nb < NN / 8; nb += gridDim.x) {
        const int i8 = nb * 192 + t;
        const u32x4 u = __builtin_nontemporal_load(conv_u4 + i8);
        f32x4 a, b;
        a.x = fmaf(__uint_as_float(u.x << 16),         sc[0], bi[0]);
        a.y = fmaf(__uint_as_float(u.x & 0xFFFF0000u), sc[1], bi[1]);
        a.z = fmaf(__uint_as_float(u.y << 16),         sc[2], bi[2]);
        a.w = fmaf(__uint_as_float(u.y & 0xFFFF0000u), sc[3], bi[3]);
        b.x = fmaf(__uint_as_float(u.z << 16),         sc[4], bi[4]);
        b.y = fmaf(__uint_as_float(u.z & 0xFFFF0000u), sc[5], bi[5]);
        b.z = fmaf(__uint_as_float(u.w << 16),         sc[6], bi[6]);
        b.w = fmaf(__uint_as_float(u.w & 0xFFFF0000u), sc[7], bi[7]);
        __builtin_nontemporal_store(a, out4 + 2 * i8);
        __builtin_nontemporal_store(b, out4 + 2 * i8 + 1);
    }
}

// ---------------------------------------------------------------------------
// Fallback tier (ws too small): fp32 conv + fused apply on fp32.
// ---------------------------------------------------------------------------
__global__ __launch_bounds__(CC) void conv_bn_partial_f32(
    const float* __restrict__ data,
    const int*   __restrict__ neigh,
    const float* __restrict__ weight,
    float*       __restrict__ conv_out,
    float*       __restrict__ ch_sum,
    float*       __restrict__ ch_sumsq)
{
    const int c = threadIdx.x;
    const int base = blockIdx.x * 32;
    float w[KK];
#pragma unroll
    for (int k = 0; k < KK; ++k) w[k] = weight[k * CC + c];
    float s = 0.f, ss = 0.f;
    for (int n = 0; n < 32; ++n) {
        const int node = base + n;
        const int* nrow = neigh + node * KK;
        float acc = 0.f;
#pragma unroll
        for (int k = 0; k < KK; ++k)
            acc = fmaf(data[nrow[k] * CC + c], w[k], acc);
        conv_out[node * CC + c] = acc;
        s += acc; ss += acc * acc;
    }
    atomicAdd(&ch_sum[c], s);
    atomicAdd(&ch_sumsq[c], ss);
}

__global__ __launch_bounds__(192) void bn_apply_f32_fused(
    float* __restrict__ out,
    const float* __restrict__ ch_sum,
    const float* __restrict__ ch_sumsq,
    const float* __restrict__ gamma,
    const float* __restrict__ beta)
{
    const int t = threadIdx.x;
    const int g = t / 48;
    const int q = t - g * 48;
    const int cb = q * 4;
    const float inv_n = 1.0f / (float)NN;
    float4 sc, bi;
    float m0 = ch_sum[cb+0]*inv_n, m1 = ch_sum[cb+1]*inv_n;
    float m2 = ch_sum[cb+2]*inv_n, m3 = ch_sum[cb+3]*inv_n;
    sc.x = gamma[cb+0]*rsqrtf(ch_sumsq[cb+0]*inv_n - m0*m0 + BN_EPS);
    sc.y = gamma[cb+1]*rsqrtf(ch_sumsq[cb+1]*inv_n - m1*m1 + BN_EPS);
    sc.z = gamma[cb+2]*rsqrtf(ch_sumsq[cb+2]*inv_n - m2*m2 + BN_EPS);
    sc.w = gamma[cb+3]*rsqrtf(ch_sumsq[cb+3]*inv_n - m3*m3 + BN_EPS);
    bi.x = beta[cb+0] - m0*sc.x; bi.y = beta[cb+1] - m1*sc.y;
    bi.z = beta[cb+2] - m2*sc.z; bi.w = beta[cb+3] - m3*sc.w;
    for (int nb = blockIdx.x; nb < NN / 4; nb += gridDim.x) {
        const int i = (nb * 4 + g) * 48 + q;
        float4 v = reinterpret_cast<float4*>(out)[i];
        v.x = fmaf(v.x, sc.x, bi.x); v.y = fmaf(v.y, sc.y, bi.y);
        v.z = fmaf(v.z, sc.z, bi.z); v.w = fmaf(v.w, sc.w, bi.w);
        reinterpret_cast<float4*>(out)[i] = v;
    }
}

extern "C" void kernel_launch(void* const* d_in, const int* in_sizes, int n_in,
                              void* d_out, int out_size, void* d_ws, size_t ws_size,
                              hipStream_t stream) {
    const float* data   = (const float*)d_in[0];
    const int*   neigh  = (const int*)  d_in[1];
    const float* weight = (const float*)d_in[2];
    const float* gamma  = (const float*)d_in[3];
    const float* beta   = (const float*)d_in[4];
    float* out = (float*)d_out;

    // ws: stats 384 floats (padded to 4096 B) | data_bf 50.3 MB | conv_bf 50.3 MB
    float* stats    = (float*)d_ws;
    float* ch_sum   = stats;
    float* ch_sumsq = stats + CC;
    unsigned short* data_bf = (unsigned short*)((char*)d_ws + 4096);
    const size_t stage_bytes = (size_t)NN * CC * sizeof(unsigned short);
    unsigned short* conv_bf =
        (unsigned short*)((char*)d_ws + 4096 + stage_bytes);

    const size_t need_full = 4096 + 2 * stage_bytes;

    if (ws_size >= need_full) {
        cvt_zero<<<2048, 256, 0, stream>>>(data, data_bf, stats);
        conv_r10<<<NN / NB, 192, 0, stream>>>(
            data_bf, neigh, weight, conv_bf, ch_sum, ch_sumsq);
        bn_apply_fused<<<4096, 192, 0, stream>>>(
            (const u32x4*)conv_bf, ch_sum, ch_sumsq, gamma, beta, out);
    } else {
        hipMemsetAsync(stats, 0, 2 * CC * sizeof(float), stream);
        conv_bn_partial_f32<<<NN / 32, CC, 0, stream>>>(
            data, neigh, weight, out, ch_sum, ch_sumsq);
        bn_apply_f32_fused<<<8192, 192, 0, stream>>>(
            out, ch_sum, ch_sumsq, gamma, beta);
    }
}